// Round 13
// baseline (186.658 us; speedup 1.0000x reference)
//
#include <hip/hip_runtime.h>

using bf16x8 = __attribute__((ext_vector_type(8))) __bf16;
using f32x4  = __attribute__((ext_vector_type(4))) float;
using u16 = unsigned short;

constexpr int Bb = 16, Nn = 512, Ee = 768, Hh = 12, Dd = 64;

__device__ inline u16 f2b(float x) {
  union { float f; unsigned int u; } v; v.f = x;
  unsigned int r = v.u + 0x7fffu + ((v.u >> 16) & 1u);
  return (u16)(r >> 16);
}

__device__ inline unsigned cvtpk(float lo, float hi) {
  unsigned r;
  asm("v_cvt_pk_bf16_f32 %0, %1, %2" : "=v"(r) : "v"(lo), "v"(hi));
  return r;
}

__device__ inline void gload16(const void* g, void* l) {
  __builtin_amdgcn_global_load_lds((const __attribute__((address_space(1))) void*)g,
                                   (__attribute__((address_space(3))) void*)l, 16, 0, 0);
}

#define MFMA __builtin_amdgcn_mfma_f32_16x16x32_bf16

// ---------- K0: weights f32->bf16, combined bias bf16(sb+eb), X f32->bf16 ----------
__global__ void k_cvt(const float* __restrict__ w0, const float* __restrict__ w1,
                      const float* __restrict__ w2, const float* __restrict__ w3,
                      u16* __restrict__ dstW,
                      const float* __restrict__ sb, const float* __restrict__ eb,
                      u16* __restrict__ cb,
                      const float* __restrict__ xq, const float* __restrict__ xk,
                      const float* __restrict__ xv, u16* __restrict__ Xb) {
  int idx = blockIdx.x * 256 + threadIdx.x;
  constexpr int perW = Ee * Ee / 4;        // 147456 float4 per matrix
  constexpr int totW = 4 * perW;           // 589824
  constexpr int totB = 524288;             // bias: 8 elems/thread
  constexpr int perX = Bb * Nn * Ee / 4;   // 1572864 float4 per X matrix
  if (idx < totW) {
    int m = idx / perW, r = idx - m * perW;
    const float* src = (m == 0) ? w0 : (m == 1) ? w1 : (m == 2) ? w2 : w3;
    float4 v = reinterpret_cast<const float4*>(src)[r];
    ushort4 o = make_ushort4(f2b(v.x), f2b(v.y), f2b(v.z), f2b(v.w));
    reinterpret_cast<ushort4*>(dstW)[idx] = o;
  } else if (idx < totW + totB) {
    int k = idx - totW;                    // [0, 524288): 8 elems each
    float4 s0 = reinterpret_cast<const float4*>(sb)[k * 2];
    float4 s1 = reinterpret_cast<const float4*>(sb)[k * 2 + 1];
    float4 e0 = reinterpret_cast<const float4*>(eb)[k * 2];
    float4 e1 = reinterpret_cast<const float4*>(eb)[k * 2 + 1];
    ushort4 o0 = make_ushort4(f2b(s0.x + e0.x), f2b(s0.y + e0.y), f2b(s0.z + e0.z), f2b(s0.w + e0.w));
    ushort4 o1 = make_ushort4(f2b(s1.x + e1.x), f2b(s1.y + e1.y), f2b(s1.z + e1.z), f2b(s1.w + e1.w));
    reinterpret_cast<ushort4*>(cb)[k * 2] = o0;
    reinterpret_cast<ushort4*>(cb)[k * 2 + 1] = o1;
  } else {
    int k3 = idx - totW - totB;            // [0, 4718592)
    int m3 = k3 / perX, r3 = k3 - m3 * perX;
    const float* src = (m3 == 0) ? xq : (m3 == 1) ? xk : xv;
    float4 v = reinterpret_cast<const float4*>(src)[r3];
    ushort4 o = make_ushort4(f2b(v.x), f2b(v.y), f2b(v.z), f2b(v.w));
    reinterpret_cast<ushort4*>(Xb + (size_t)m3 * (Bb * Nn * Ee))[r3] = o;
  }
}

// ---------- K1: QKV projection GEMM — all-bf16 staging, 34KB LDS, 4 blocks/CU ----------
__global__ __launch_bounds__(256, 4)
void k_qkv(const u16* __restrict__ Xb, const u16* __restrict__ wb,
           const float* __restrict__ bq, const float* __restrict__ bk,
           const float* __restrict__ bv, u16* __restrict__ Q, u16* __restrict__ K,
           u16* __restrict__ VT) {
  const int mat = blockIdx.z;
  const u16* X = Xb + (size_t)mat * (Bb * Nn * Ee);
  const u16* W = wb + (size_t)mat * Ee * Ee;
  const float* bias = (mat == 0) ? bq : (mat == 1) ? bk : bv;
  const int bm = blockIdx.x, bn = blockIdx.y;
  const int tid = threadIdx.x, lane = tid & 63, wid = tid >> 6;
  const int wr = wid >> 1, wc = wid & 1;

  __shared__ char smem[34816];   // staging: A 2x8KB at 0, B 2x8KB at 16384; epilogue [128][136]u16

  auto stageA = [&](int buf, int it) {
    const int r0 = tid >> 2, s = tid & 3;
    char* lbase = smem + buf * 8192 + tid * 16;
#pragma unroll
    for (int R = 0; R < 2; ++R) {
      const int row = R * 64 + r0;
      const int ch = s ^ ((row >> 1) & 3);
      gload16(X + (size_t)(bm * 128 + row) * Ee + it * 32 + ch * 8, lbase + R * 4096);
    }
  };
  auto stageB = [&](int buf, int it) {
    const int r0 = tid >> 2, s = tid & 3;
    char* lbase = smem + 16384 + buf * 8192 + tid * 16;
#pragma unroll
    for (int R = 0; R < 2; ++R) {
      const int row = R * 64 + r0;
      const int ch = s ^ ((row >> 1) & 3);
      gload16(W + (size_t)(bn * 128 + row) * Ee + it * 32 + ch * 8, lbase + R * 4096);
    }
  };

  f32x4 acc[4][4] = {};

  auto compute = [&](int buf) {
    const char* Ab = smem + buf * 8192;
    const char* Bbp = smem + 16384 + buf * 8192;
    const int q = lane >> 4;
    bf16x8 a[4], b[4];
#pragma unroll
    for (int mt = 0; mt < 4; ++mt) {
      const int row = wr * 64 + mt * 16 + (lane & 15);
      const int s = q ^ ((row >> 1) & 3);
      a[mt] = *reinterpret_cast<const bf16x8*>(Ab + row * 64 + s * 16);
    }
#pragma unroll
    for (int nt = 0; nt < 4; ++nt) {
      const int row = wc * 64 + nt * 16 + (lane & 15);
      const int s = q ^ ((row >> 1) & 3);
      b[nt] = *reinterpret_cast<const bf16x8*>(Bbp + row * 64 + s * 16);
    }
#pragma unroll
    for (int mt = 0; mt < 4; ++mt)
#pragma unroll
      for (int nt = 0; nt < 4; ++nt)
        acc[mt][nt] = MFMA(a[mt], b[nt], acc[mt][nt], 0, 0, 0);
  };

  stageA(0, 0); stageB(0, 0);
  __syncthreads();
  int buf = 0;
  for (int it = 0; it < 24; ++it) {
    if (it + 1 < 24) { stageA(buf ^ 1, it + 1); stageB(buf ^ 1, it + 1); }
    compute(buf);
    __syncthreads();
    buf ^= 1;
  }

  // epilogue via LDS transpose tile [128][136] u16 for coalesced 128B stores
  u16* sm16 = (u16*)smem;
  if (mat < 2) {
    u16* dst = (mat == 0) ? Q : K;
    const float sc = (mat == 0) ? 0.125f : 1.0f;
#pragma unroll
    for (int mt = 0; mt < 4; ++mt) {
      const int n_l0 = wr * 64 + mt * 16 + ((lane >> 4) << 2);
#pragma unroll
      for (int nt = 0; nt < 4; ++nt) {
        const int e_l = wc * 64 + nt * 16 + (lane & 15);
        const float bs = bias[bn * 128 + e_l];
#pragma unroll
        for (int j = 0; j < 4; ++j)
          sm16[(n_l0 + j) * 136 + e_l] = f2b((acc[mt][nt][j] + bs) * sc);
      }
    }
    __syncthreads();
    const int row = tid >> 1, half = tid & 1;
    const int n = bm * 128 + row, b = n >> 9, n0 = n & 511, h = bn * 2 + half;
    u16* gp = dst + ((size_t)(b * Hh + h) * Nn + n0) * Dd;
    const u16* sp = sm16 + row * 136 + half * 64;
#pragma unroll
    for (int i = 0; i < 8; ++i)
      *reinterpret_cast<int4*>(gp + i * 8) = *reinterpret_cast<const int4*>(sp + i * 8);
  } else {
#pragma unroll
    for (int mt = 0; mt < 4; ++mt) {
      const int n_l0 = wr * 64 + mt * 16 + ((lane >> 4) << 2);
#pragma unroll
      for (int nt = 0; nt < 4; ++nt) {
        const int e_l = wc * 64 + nt * 16 + (lane & 15);
        const float bs = bias[bn * 128 + e_l];
#pragma unroll
        for (int j = 0; j < 4; ++j)
          sm16[e_l * 136 + n_l0 + j] = f2b(acc[mt][nt][j] + bs);
      }
    }
    __syncthreads();
    const int er = tid >> 1, half = tid & 1;
    const int b = bm >> 2, h = bn * 2 + (er >> 6), d = er & 63;
    u16* gp = VT + ((size_t)(b * Hh + h) * Dd + d) * Nn + (bm & 3) * 128 + half * 64;
    const u16* sp = sm16 + er * 136 + half * 64;
#pragma unroll
    for (int i = 0; i < 8; ++i)
      *reinterpret_cast<int4*>(gp + i * 8) = *reinterpret_cast<const int4*>(sp + i * 8);
  }
}

// ---------- K2: FUSED attn (unchanged from R12) ----------
__global__ __launch_bounds__(256, 2)
void k_attn(const u16* __restrict__ Q, const u16* __restrict__ K,
            const u16* __restrict__ cb, const u16* __restrict__ VT,
            float* __restrict__ wout, u16* __restrict__ AO) {
  const int flat = blockIdx.x + 8 * (blockIdx.y + Hh * blockIdx.z);   // [0,1536)
  const int c = flat & 7, j = flat >> 3;
  const int g = c + 8 * (j % 24);
  const int qb = j / 24;
  const int h = g % Hh, b = g / Hh;
  const int bh = b * Hh + h;
  const int q0 = qb * 64;
  const int tid = threadIdx.x, lane = tid & 63, wid = tid >> 6;
  const int l15 = lane & 15, q4 = lane >> 4;

  __shared__ char smem[65536];
  __shared__ u16 ao_t[64 * 72];

  bf16x8 aq[2];
  {
    const u16* qp = Q + ((size_t)bh * Nn + q0 + wid * 16 + l15) * Dd + q4 * 8;
    aq[0] = *reinterpret_cast<const bf16x8*>(qp);
    aq[1] = *reinterpret_cast<const bf16x8*>(qp + 32);
  }

  const int rql = wid * 16 + l15;
  const int rq = q0 + rql;
  const u16* cbp = cb + ((size_t)b * Nn + rq) * Nn + q4 * 4;
  uint2 cbr[32];
#pragma unroll
  for (int t = 0; t < 32; ++t)
    cbr[t] = *reinterpret_cast<const uint2*>(cbp + t * 16);

#pragma unroll
  for (int i = 0; i < 8; ++i) {
    const int s = i * 256 + tid;
    const int row = s >> 3, cs = s & 7;
    gload16(K + ((size_t)bh * Nn + row) * Dd + (cs ^ (row & 7)) * 8, smem + s * 16);
  }
  __syncthreads();

#pragma unroll
  for (int i = 8; i < 16; ++i) {
    const int s = i * 256 + tid;
    const int row = s >> 3, cs = s & 7;
    gload16(K + ((size_t)bh * Nn + row) * Dd + (cs ^ (row & 7)) * 8, smem + s * 16);
  }

  f32x4 acc[32] = {};
  __builtin_amdgcn_s_setprio(1);
#pragma unroll
  for (int kt = 0; kt < 4; ++kt)
#pragma unroll
    for (int kk = 0; kk < 2; ++kk)
#pragma unroll
      for (int ct = 0; ct < 4; ++ct) {
        const int r = kt * 64 + ct * 16 + l15;
        bf16x8 bk = *reinterpret_cast<const bf16x8*>(
            smem + r * 128 + (((kk * 4 + q4) ^ (r & 7)) * 16));
        acc[kt * 4 + ct] = MFMA(bk, aq[kk], acc[kt * 4 + ct], 0, 0, 0);
      }
  __builtin_amdgcn_s_setprio(0);
  __syncthreads();

  __builtin_amdgcn_s_setprio(1);
#pragma unroll
  for (int kt = 4; kt < 8; ++kt)
#pragma unroll
    for (int kk = 0; kk < 2; ++kk)
#pragma unroll
      for (int ct = 0; ct < 4; ++ct) {
        const int r = kt * 64 + ct * 16 + l15;
        bf16x8 bk = *reinterpret_cast<const bf16x8*>(
            smem + r * 128 + (((kk * 4 + q4) ^ (r & 7)) * 16));
        acc[kt * 4 + ct] = MFMA(bk, aq[kk], acc[kt * 4 + ct], 0, 0, 0);
      }
  __builtin_amdgcn_s_setprio(0);

#pragma unroll
  for (int t = 0; t < 32; ++t) {
    acc[t][0] += __uint_as_float((unsigned)cbr[t].x << 16);
    acc[t][1] += __uint_as_float(cbr[t].x & 0xffff0000u);
    acc[t][2] += __uint_as_float((unsigned)cbr[t].y << 16);
    acc[t][3] += __uint_as_float(cbr[t].y & 0xffff0000u);
  }

  float mx = -1e30f;
#pragma unroll
  for (int t = 0; t < 32; ++t)
#pragma unroll
    for (int j2 = 0; j2 < 4; ++j2) mx = fmaxf(mx, acc[t][j2]);
  mx = fmaxf(mx, __shfl_xor(mx, 16));
  mx = fmaxf(mx, __shfl_xor(mx, 32));

  float sum = 0.f;
#pragma unroll
  for (int t = 0; t < 32; ++t)
#pragma unroll
    for (int j2 = 0; j2 < 4; ++j2) {
      float p = exp2f((acc[t][j2] - mx) * 1.44269504f);
      acc[t][j2] = p;
      sum += p;
    }
  sum += __shfl_xor(sum, 16);
  sum += __shfl_xor(sum, 32);
  const float inv = 1.0f / sum;

  __syncthreads();

  const u16* Vb = VT + ((size_t)bh * Dd + l15) * Nn + q4 * 8;
  bf16x8 vb0[8], vb1[8];
  auto loadV = [&](int kt, bf16x8* d) {
#pragma unroll
    for (int kk = 0; kk < 2; ++kk)
#pragma unroll
      for (int ct = 0; ct < 4; ++ct)
        d[kk * 4 + ct] = *reinterpret_cast<const bf16x8*>(
            Vb + (size_t)(ct * 16) * Nn + kt * 64 + kk * 32);
  };
  loadV(0, vb0);
  loadV(1, vb1);

  char* Pb = smem + rql * 1024;
#pragma unroll
  for (int t = 0; t < 32; ++t) {
    acc[t][0] *= inv; acc[t][1] *= inv; acc[t][2] *= inv; acc[t][3] *= inv;
    uint2 pk;
    pk.x = cvtpk(acc[t][0], acc[t][1]);
    pk.y = cvtpk(acc[t][2], acc[t][3]);
    const int chunk = (2 * t + (q4 >> 1)) ^ (rql & 7);
    *reinterpret_cast<uint2*>(Pb + chunk * 16 + (q4 & 1) * 8) = pk;
  }
  __syncthreads();

  f32x4 acc2[4] = {};
  const int qr = rql;
  const char* Pr = smem + qr * 1024;
  f32x4* wp4 = reinterpret_cast<f32x4*>(wout + ((size_t)bh * Nn + rq) * Nn);
  auto storeW = [&](int kt) {
#pragma unroll
    for (int u = 0; u < 4; ++u) {
      const int t = kt * 4 + u;
      __builtin_nontemporal_store(acc[t], &wp4[t * 4 + q4]);
    }
  };
#pragma unroll
  for (int kp = 0; kp < 4; ++kp) {
    const int ktA = 2 * kp, ktB = 2 * kp + 1;
    __builtin_amdgcn_s_setprio(1);
#pragma unroll
    for (int kk = 0; kk < 2; ++kk) {
      const int chunk = (ktA * 8 + kk * 4 + q4) ^ (qr & 7);
      bf16x8 pa = *reinterpret_cast<const bf16x8*>(Pr + chunk * 16);
#pragma unroll
      for (int ct = 0; ct < 4; ++ct)
        acc2[ct] = MFMA(pa, vb0[kk * 4 + ct], acc2[ct], 0, 0, 0);
    }
    __builtin_amdgcn_s_setprio(0);
    if (ktA + 2 < 8) loadV(ktA + 2, vb0);
    storeW(ktA);
    __builtin_amdgcn_s_setprio(1);
#pragma unroll
    for (int kk = 0; kk < 2; ++kk) {
      const int chunk = (ktB * 8 + kk * 4 + q4) ^ (qr & 7);
      bf16x8 pa = *reinterpret_cast<const bf16x8*>(Pr + chunk * 16);
#pragma unroll
      for (int ct = 0; ct < 4; ++ct)
        acc2[ct] = MFMA(pa, vb1[kk * 4 + ct], acc2[ct], 0, 0, 0);
    }
    __builtin_amdgcn_s_setprio(0);
    if (ktB + 2 < 8) loadV(ktB + 2, vb1);
    storeW(ktB);
  }

#pragma unroll
  for (int ct = 0; ct < 4; ++ct)
#pragma unroll
    for (int j2 = 0; j2 < 4; ++j2)
      ao_t[(wid * 16 + q4 * 4 + j2) * 72 + ct * 16 + l15] = f2b(acc2[ct][j2]);
  __syncthreads();
  {
    const int row = tid >> 3, ch = tid & 7;
#pragma unroll
    for (int i = 0; i < 2; ++i) {
      const int r = row + i * 32;
      int4 v = *reinterpret_cast<const int4*>(ao_t + r * 72 + ch * 8);
      *reinterpret_cast<int4*>(AO + ((size_t)b * Nn + q0 + r) * Ee + h * Dd + ch * 8) = v;
    }
  }
}

// ---------- K4: output projection GEMM (unchanged) ----------
__global__ __launch_bounds__(256, 4)
void k_outproj(const u16* __restrict__ AOp, const u16* __restrict__ Wo,
               const float* __restrict__ bo, float* __restrict__ out) {
  const int bm = blockIdx.x, bn = blockIdx.y;
  const int tid = threadIdx.x, lane = tid & 63, wid = tid >> 6;
  const int wr = wid >> 1, wc = wid & 1;

  __shared__ char smem[32768];

  auto stage = [&](const u16* src, int lds_base, int buf, int it) {
    const int r0 = tid >> 2, s = tid & 3;
    char* lbase = smem + lds_base + buf * 8192 + tid * 16;
#pragma unroll
    for (int R = 0; R < 2; ++R) {
      const int row = R * 64 + r0;
      const int ch = s ^ ((row >> 1) & 3);
      gload16(src + (size_t)row * Ee + it * 32 + ch * 8, lbase + R * 4096);
    }
  };

  f32x4 acc[4][4] = {};

  auto compute = [&](int buf) {
    const char* Ab = smem + buf * 8192;
    const char* Bbp = smem + 16384 + buf * 8192;
    const int q = lane >> 4;
    bf16x8 a[4], b[4];
#pragma unroll
    for (int mt = 0; mt < 4; ++mt) {
      const int row = wr * 64 + mt * 16 + (lane & 15);
      const int s = q ^ ((row >> 1) & 3);
      a[mt] = *reinterpret_cast<const bf16x8*>(Ab + row * 64 + s * 16);
    }
#pragma unroll
    for (int nt = 0; nt < 4; ++nt) {
      const int row = wc * 64 + nt * 16 + (lane & 15);
      const int s = q ^ ((row >> 1) & 3);
      b[nt] = *reinterpret_cast<const bf16x8*>(Bbp + row * 64 + s * 16);
    }
#pragma unroll
    for (int mt = 0; mt < 4; ++mt)
#pragma unroll
      for (int nt = 0; nt < 4; ++nt)
        acc[mt][nt] = MFMA(a[mt], b[nt], acc[mt][nt], 0, 0, 0);
  };

  const u16* Asrc = AOp + (size_t)(bm * 128) * Ee;
  const u16* Bsrc = Wo + (size_t)(bn * 128) * Ee;
  stage(Asrc, 0, 0, 0); stage(Bsrc, 16384, 0, 0);
  __syncthreads();
  int buf = 0;
  for (int it = 0; it < 24; ++it) {
    if (it + 1 < 24) { stage(Asrc, 0, buf ^ 1, it + 1); stage(Bsrc, 16384, buf ^ 1, it + 1); }
    compute(buf);
    __syncthreads();
    buf ^= 1;
  }

#pragma unroll
  for (int mt = 0; mt < 4; ++mt) {
#pragma unroll
    for (int nt = 0; nt < 4; ++nt) {
      const int ecol = bn * 128 + wc * 64 + nt * 16 + (lane & 15);
      const int r0 = bm * 128 + wr * 64 + mt * 16 + ((lane >> 4) << 2);
      const float bs = bo[ecol];
      f32x4 v = acc[mt][nt];
#pragma unroll
      for (int j = 0; j < 4; ++j)
        __builtin_nontemporal_store(v[j] + bs, &out[(size_t)(r0 + j) * Ee + ecol]);
    }
  }
}

// ---------- launch ----------
extern "C" void kernel_launch(void* const* d_in, const int* in_sizes, int n_in,
                              void* d_out, int out_size, void* d_ws, size_t ws_size,
                              hipStream_t stream) {
  const float* query  = (const float*)d_in[0];
  const float* key_in = (const float*)d_in[1];
  const float* value  = (const float*)d_in[2];
  const float* sb     = (const float*)d_in[3];
  const float* eb     = (const float*)d_in[4];
  const float* Wq     = (const float*)d_in[5];
  const float* bq     = (const float*)d_in[6];
  const float* Wk     = (const float*)d_in[7];
  const float* bk     = (const float*)d_in[8];
  const float* Wv     = (const float*)d_in[9];
  const float* bv     = (const float*)d_in[10];
  const float* Wo     = (const float*)d_in[11];
  const float* bo     = (const float*)d_in[12];

  float* out0 = (float*)d_out;                        // attn_output [16,512,768]
  float* wout = out0 + (size_t)Bb * Nn * Ee;          // attn_weights [16,12,512,512]
  // Xb scratch lives in the wout region: written by k_cvt, dead after k_qkv,
  // then k_attn fully overwrites wout. 37.75 MB << 201 MB region.
  u16* Xb = (u16*)wout;

  // workspace layout (bytes)
  char* ws = (char*)d_ws;
  const size_t off_wb = 0;                 // 4 * 768*768 bf16 = 4,718,592
  const size_t off_Q  = 4718592;           // 12,582,912 each
  const size_t off_K  = 17301504;
  const size_t off_VT = 29884416;
  const size_t off_AO = 42467328;
  const size_t off_cb = 55050240;          // 16*512*512 bf16 = 8,388,608 -> end 63,438,848
  if (ws_size < 63438848) return;

  u16* wb  = (u16*)(ws + off_wb);
  u16* Qs  = (u16*)(ws + off_Q);
  u16* Kst = (u16*)(ws + off_K);
  u16* VTs = (u16*)(ws + off_VT);
  u16* AO  = (u16*)(ws + off_AO);
  u16* cbf = (u16*)(ws + off_cb);

  k_cvt<<<22784, 256, 0, stream>>>(Wq, Wk, Wv, Wo, wb, sb, eb, cbf, query, key_in, value, Xb);
  k_qkv<<<dim3(64, 6, 3), 256, 0, stream>>>(Xb, wb, bq, bk, bv, Qs, Kst, VTs);
  k_attn<<<dim3(8, Hh, Bb), 256, 0, stream>>>(Qs, Kst, cbf, VTs, wout, AO);
  k_outproj<<<dim3(64, 6), 256, 0, stream>>>(AO, wb + 3 * Ee * Ee, bo, out0);
}

// Round 14
// 170.478 us; speedup vs baseline: 1.0949x; 1.0949x over previous
//
#include <hip/hip_runtime.h>

using bf16x8 = __attribute__((ext_vector_type(8))) __bf16;
using f32x4  = __attribute__((ext_vector_type(4))) float;
using u16 = unsigned short;

constexpr int Bb = 16, Nn = 512, Ee = 768, Hh = 12, Dd = 64;

__device__ inline u16 f2b(float x) {
  union { float f; unsigned int u; } v; v.f = x;
  unsigned int r = v.u + 0x7fffu + ((v.u >> 16) & 1u);
  return (u16)(r >> 16);
}

__device__ inline unsigned cvtpk(float lo, float hi) {
  unsigned r;
  asm("v_cvt_pk_bf16_f32 %0, %1, %2" : "=v"(r) : "v"(lo), "v"(hi));
  return r;
}

__device__ inline void gload16(const void* g, void* l) {
  __builtin_amdgcn_global_load_lds((const __attribute__((address_space(1))) void*)g,
                                   (__attribute__((address_space(3))) void*)l, 16, 0, 0);
}

#define MFMA __builtin_amdgcn_mfma_f32_16x16x32_bf16

// ---------- K0: convert weights f32->bf16 AND combined bias bf16(sb+eb), one launch ----------
__global__ void k_cvt(const float* __restrict__ w0, const float* __restrict__ w1,
                      const float* __restrict__ w2, const float* __restrict__ w3,
                      u16* __restrict__ dstW,
                      const float* __restrict__ sb, const float* __restrict__ eb,
                      u16* __restrict__ cb) {
  int idx = blockIdx.x * 256 + threadIdx.x;
  constexpr int perW = Ee * Ee / 4;        // 147456 float4 per matrix
  constexpr int totW = 4 * perW;           // 589824 -> 2304 blocks
  if (idx < totW) {
    int m = idx / perW, r = idx - m * perW;
    const float* src = (m == 0) ? w0 : (m == 1) ? w1 : (m == 2) ? w2 : w3;
    float4 v = reinterpret_cast<const float4*>(src)[r];
    ushort4 o = make_ushort4(f2b(v.x), f2b(v.y), f2b(v.z), f2b(v.w));
    reinterpret_cast<ushort4*>(dstW)[idx] = o;
  } else {
    int k = idx - totW;                    // [0, 524288): 8 elems each
    float4 s0 = reinterpret_cast<const float4*>(sb)[k * 2];
    float4 s1 = reinterpret_cast<const float4*>(sb)[k * 2 + 1];
    float4 e0 = reinterpret_cast<const float4*>(eb)[k * 2];
    float4 e1 = reinterpret_cast<const float4*>(eb)[k * 2 + 1];
    ushort4 o0 = make_ushort4(f2b(s0.x + e0.x), f2b(s0.y + e0.y), f2b(s0.z + e0.z), f2b(s0.w + e0.w));
    ushort4 o1 = make_ushort4(f2b(s1.x + e1.x), f2b(s1.y + e1.y), f2b(s1.z + e1.z), f2b(s1.w + e1.w));
    reinterpret_cast<ushort4*>(cb)[k * 2] = o0;
    reinterpret_cast<ushort4*>(cb)[k * 2 + 1] = o1;
  }
}

// ---------- K1: QKV projection GEMM, global_load_lds staging (f32 A, bf16 W) ----------
__global__ __launch_bounds__(256, 3)
void k_qkv(const float* __restrict__ xq, const float* __restrict__ xk, const float* __restrict__ xv,
           const u16* __restrict__ wb, const float* __restrict__ bq, const float* __restrict__ bk,
           const float* __restrict__ bv, u16* __restrict__ Q, u16* __restrict__ K,
           u16* __restrict__ VT) {
  const int mat = blockIdx.z;
  const float* X = (mat == 0) ? xq : (mat == 1) ? xk : xv;
  const u16* W = wb + (size_t)mat * Ee * Ee;
  const float* bias = (mat == 0) ? bq : (mat == 1) ? bk : bv;
  const int bm = blockIdx.x, bn = blockIdx.y;
  const int tid = threadIdx.x, lane = tid & 63, wid = tid >> 6;
  const int wr = wid >> 1, wc = wid & 1;

  __shared__ char smem[49152];   // A: 2x16KB at 0; B: 2x8KB at 32768

  auto stageA = [&](int buf, int it) {
    const int r0 = tid >> 3, s = tid & 7;
    char* lbase = smem + buf * 16384 + tid * 16;
#pragma unroll
    for (int R = 0; R < 4; ++R) {
      const int row = R * 32 + r0;
      const int ch = s ^ (row & 7);
      gload16(X + (size_t)(bm * 128 + row) * Ee + it * 32 + ch * 4, lbase + R * 4096);
    }
  };
  auto stageB = [&](int buf, int it) {
    const int r0 = tid >> 2, s = tid & 3;
    char* lbase = smem + 32768 + buf * 8192 + tid * 16;
#pragma unroll
    for (int R = 0; R < 2; ++R) {
      const int row = R * 64 + r0;
      const int ch = s ^ ((row >> 1) & 3);
      gload16(W + (size_t)(bn * 128 + row) * Ee + it * 32 + ch * 8, lbase + R * 4096);
    }
  };

  f32x4 acc[4][4] = {};

  auto compute = [&](int buf) {
    const char* Ab = smem + buf * 16384;
    const char* Bbp = smem + 32768 + buf * 8192;
    const int q = lane >> 4;
    bf16x8 a[4], b[4];
#pragma unroll
    for (int mt = 0; mt < 4; ++mt) {
      const int row = wr * 64 + mt * 16 + (lane & 15);
      const int s0 = (2 * q) ^ (row & 7), s1 = (2 * q + 1) ^ (row & 7);
      f32x4 f0 = *reinterpret_cast<const f32x4*>(Ab + row * 128 + s0 * 16);
      f32x4 f1 = *reinterpret_cast<const f32x4*>(Ab + row * 128 + s1 * 16);
      union { unsigned u[4]; bf16x8 v; } cv;
      cv.u[0] = cvtpk(f0[0], f0[1]);
      cv.u[1] = cvtpk(f0[2], f0[3]);
      cv.u[2] = cvtpk(f1[0], f1[1]);
      cv.u[3] = cvtpk(f1[2], f1[3]);
      a[mt] = cv.v;
    }
#pragma unroll
    for (int nt = 0; nt < 4; ++nt) {
      const int row = wc * 64 + nt * 16 + (lane & 15);
      const int s = q ^ ((row >> 1) & 3);
      b[nt] = *reinterpret_cast<const bf16x8*>(Bbp + row * 64 + s * 16);
    }
#pragma unroll
    for (int mt = 0; mt < 4; ++mt)
#pragma unroll
      for (int nt = 0; nt < 4; ++nt)
        acc[mt][nt] = MFMA(a[mt], b[nt], acc[mt][nt], 0, 0, 0);
  };

  stageA(0, 0); stageB(0, 0);
  __syncthreads();
  int buf = 0;
  for (int it = 0; it < 24; ++it) {
    if (it + 1 < 24) { stageA(buf ^ 1, it + 1); stageB(buf ^ 1, it + 1); }
    compute(buf);
    __syncthreads();
    buf ^= 1;
  }

  // epilogue via LDS transpose tile [128][136] u16 for coalesced 128B stores
  u16* sm16 = (u16*)smem;
  if (mat < 2) {
    u16* dst = (mat == 0) ? Q : K;
    const float sc = (mat == 0) ? 0.125f : 1.0f;
#pragma unroll
    for (int mt = 0; mt < 4; ++mt) {
      const int n_l0 = wr * 64 + mt * 16 + ((lane >> 4) << 2);
#pragma unroll
      for (int nt = 0; nt < 4; ++nt) {
        const int e_l = wc * 64 + nt * 16 + (lane & 15);
        const float bs = bias[bn * 128 + e_l];
#pragma unroll
        for (int j = 0; j < 4; ++j)
          sm16[(n_l0 + j) * 136 + e_l] = f2b((acc[mt][nt][j] + bs) * sc);
      }
    }
    __syncthreads();
    const int row = tid >> 1, half = tid & 1;
    const int n = bm * 128 + row, b = n >> 9, n0 = n & 511, h = bn * 2 + half;
    u16* gp = dst + ((size_t)(b * Hh + h) * Nn + n0) * Dd;
    const u16* sp = sm16 + row * 136 + half * 64;
#pragma unroll
    for (int i = 0; i < 8; ++i)
      *reinterpret_cast<int4*>(gp + i * 8) = *reinterpret_cast<const int4*>(sp + i * 8);
  } else {
#pragma unroll
    for (int mt = 0; mt < 4; ++mt) {
      const int n_l0 = wr * 64 + mt * 16 + ((lane >> 4) << 2);
#pragma unroll
      for (int nt = 0; nt < 4; ++nt) {
        const int e_l = wc * 64 + nt * 16 + (lane & 15);
        const float bs = bias[bn * 128 + e_l];
#pragma unroll
        for (int j = 0; j < 4; ++j)
          sm16[e_l * 136 + n_l0 + j] = f2b(acc[mt][nt][j] + bs);
      }
    }
    __syncthreads();
    const int er = tid >> 1, half = tid & 1;
    const int b = bm >> 2, h = bn * 2 + (er >> 6), d = er & 63;
    u16* gp = VT + ((size_t)(b * Hh + h) * Dd + d) * Nn + (bm & 3) * 128 + half * 64;
    const u16* sp = sm16 + er * 136 + half * 64;
#pragma unroll
    for (int i = 0; i < 8; ++i)
      *reinterpret_cast<int4*>(gp + i * 8) = *reinterpret_cast<const int4*>(sp + i * 8);
  }
}

// ---------- K2: FUSED attn — b-colocating XCD swizzle (cb+K+V+Q all L2-hot per XCD) ----------
__global__ __launch_bounds__(256, 2)
void k_attn(const u16* __restrict__ Q, const u16* __restrict__ K,
            const u16* __restrict__ cb, const u16* __restrict__ VT,
            float* __restrict__ wout, u16* __restrict__ AO) {
  // b-colocation: XCD c gets b = 2c and 2c+1 (96 blocks each: 12 h x 8 qb).
  // Per-b working set cb 512KB + 12x(K+V+Q) ~ 2.2MB fits the XCD's 4MB L2.
  const int flat = blockIdx.x + 8 * (blockIdx.y + Hh * blockIdx.z);   // [0,1536)
  const int c = flat & 7, j = flat >> 3;          // c = XCD, j in [0,192)
  const int b = 2 * c + (j / 96);
  const int j2 = j % 96;
  const int h = j2 >> 3, qb = j2 & 7;
  const int bh = b * Hh + h;
  const int q0 = qb * 64;
  const int tid = threadIdx.x, lane = tid & 63, wid = tid >> 6;
  const int l15 = lane & 15, q4 = lane >> 4;

  __shared__ char smem[65536];     // phase1: K[512][64] bf16 swizzled; phase2: P[64][512]
  __shared__ u16 ao_t[64 * 72];    // dedicated epilogue transpose (9216B)

  bf16x8 aq[2];
  {
    const u16* qp = Q + ((size_t)bh * Nn + q0 + wid * 16 + l15) * Dd + q4 * 8;
    aq[0] = *reinterpret_cast<const bf16x8*>(qp);
    aq[1] = *reinterpret_cast<const bf16x8*>(qp + 32);
  }

  // issue ALL 32 bias loads now — they drain under the K-stage vmcnt wait
  const int rql = wid * 16 + l15;          // local q row [0,64)
  const int rq = q0 + rql;
  const u16* cbp = cb + ((size_t)b * Nn + rq) * Nn + q4 * 4;
  uint2 cbr[32];
#pragma unroll
  for (int t = 0; t < 32; ++t)
    cbr[t] = *reinterpret_cast<const uint2*>(cbp + t * 16);

  // stage K half 0 (rows 0..255)
#pragma unroll
  for (int i = 0; i < 8; ++i) {
    const int s = i * 256 + tid;
    const int row = s >> 3, cs = s & 7;
    gload16(K + ((size_t)bh * Nn + row) * Dd + (cs ^ (row & 7)) * 8, smem + s * 16);
  }
  __syncthreads();

  // issue stage of K half 1 (rows 256..511), then QK^T on half 0 (loads overlap MFMAs)
#pragma unroll
  for (int i = 8; i < 16; ++i) {
    const int s = i * 256 + tid;
    const int row = s >> 3, cs = s & 7;
    gload16(K + ((size_t)bh * Nn + row) * Dd + (cs ^ (row & 7)) * 8, smem + s * 16);
  }

  f32x4 acc[32] = {};
  __builtin_amdgcn_s_setprio(1);
#pragma unroll
  for (int kt = 0; kt < 4; ++kt)
#pragma unroll
    for (int kk = 0; kk < 2; ++kk)
#pragma unroll
      for (int ct = 0; ct < 4; ++ct) {
        const int r = kt * 64 + ct * 16 + l15;
        bf16x8 bk = *reinterpret_cast<const bf16x8*>(
            smem + r * 128 + (((kk * 4 + q4) ^ (r & 7)) * 16));
        acc[kt * 4 + ct] = MFMA(bk, aq[kk], acc[kt * 4 + ct], 0, 0, 0);
      }
  __builtin_amdgcn_s_setprio(0);
  __syncthreads();   // half-1 staged

  __builtin_amdgcn_s_setprio(1);
#pragma unroll
  for (int kt = 4; kt < 8; ++kt)
#pragma unroll
    for (int kk = 0; kk < 2; ++kk)
#pragma unroll
      for (int ct = 0; ct < 4; ++ct) {
        const int r = kt * 64 + ct * 16 + l15;
        bf16x8 bk = *reinterpret_cast<const bf16x8*>(
            smem + r * 128 + (((kk * 4 + q4) ^ (r & 7)) * 16));
        acc[kt * 4 + ct] = MFMA(bk, aq[kk], acc[kt * 4 + ct], 0, 0, 0);
      }
  __builtin_amdgcn_s_setprio(0);

  // bias add from prefetched registers
#pragma unroll
  for (int t = 0; t < 32; ++t) {
    acc[t][0] += __uint_as_float((unsigned)cbr[t].x << 16);
    acc[t][1] += __uint_as_float(cbr[t].x & 0xffff0000u);
    acc[t][2] += __uint_as_float((unsigned)cbr[t].y << 16);
    acc[t][3] += __uint_as_float(cbr[t].y & 0xffff0000u);
  }

  // softmax over the 512-wide row (row lives in 4 lanes {16,32} apart)
  float mx = -1e30f;
#pragma unroll
  for (int t = 0; t < 32; ++t)
#pragma unroll
    for (int j3 = 0; j3 < 4; ++j3) mx = fmaxf(mx, acc[t][j3]);
  mx = fmaxf(mx, __shfl_xor(mx, 16));
  mx = fmaxf(mx, __shfl_xor(mx, 32));

  float sum = 0.f;
#pragma unroll
  for (int t = 0; t < 32; ++t)
#pragma unroll
    for (int j3 = 0; j3 < 4; ++j3) {
      float p = exp2f((acc[t][j3] - mx) * 1.44269504f);
      acc[t][j3] = p;
      sum += p;
    }
  sum += __shfl_xor(sum, 16);
  sum += __shfl_xor(sum, 32);
  const float inv = 1.0f / sum;

  __syncthreads();   // all waves done reading K LDS before overwriting with P

  // pre-issue V kt=0,1 so their latency hides under the P-pack loop
  const u16* Vb = VT + ((size_t)bh * Dd + l15) * Nn + q4 * 8;
  bf16x8 vb0[8], vb1[8];
  auto loadV = [&](int kt, bf16x8* d) {
#pragma unroll
    for (int kk = 0; kk < 2; ++kk)
#pragma unroll
      for (int ct = 0; ct < 4; ++ct)
        d[kk * 4 + ct] = *reinterpret_cast<const bf16x8*>(
            Vb + (size_t)(ct * 16) * Nn + kt * 64 + kk * 32);
  };
  loadV(0, vb0);
  loadV(1, vb1);

  // normalize acc in place + pack bf16 P into swizzled LDS (wout stores deferred to PV)
  char* Pb = smem + rql * 1024;
#pragma unroll
  for (int t = 0; t < 32; ++t) {
    acc[t][0] *= inv; acc[t][1] *= inv; acc[t][2] *= inv; acc[t][3] *= inv;
    uint2 pk;
    pk.x = cvtpk(acc[t][0], acc[t][1]);
    pk.y = cvtpk(acc[t][2], acc[t][3]);
    const int chunk = (2 * t + (q4 >> 1)) ^ (rql & 7);
    *reinterpret_cast<uint2*>(Pb + chunk * 16 + (q4 & 1) * 8) = pk;
  }
  __syncthreads();

  // PV with depth-2 V prefetch; wout nt-stores (already-normalized acc) interleaved
  f32x4 acc2[4] = {};
  const int qr = rql;
  const char* Pr = smem + qr * 1024;
  f32x4* wp4 = reinterpret_cast<f32x4*>(wout + ((size_t)bh * Nn + rq) * Nn);
  auto storeW = [&](int kt) {
#pragma unroll
    for (int u = 0; u < 4; ++u) {
      const int t = kt * 4 + u;
      __builtin_nontemporal_store(acc[t], &wp4[t * 4 + q4]);
    }
  };
#pragma unroll
  for (int kp = 0; kp < 4; ++kp) {
    const int ktA = 2 * kp, ktB = 2 * kp + 1;
    __builtin_amdgcn_s_setprio(1);
#pragma unroll
    for (int kk = 0; kk < 2; ++kk) {
      const int chunk = (ktA * 8 + kk * 4 + q4) ^ (qr & 7);
      bf16x8 pa = *reinterpret_cast<const bf16x8*>(Pr + chunk * 16);
#pragma unroll
      for (int ct = 0; ct < 4; ++ct)
        acc2[ct] = MFMA(pa, vb0[kk * 4 + ct], acc2[ct], 0, 0, 0);
    }
    __builtin_amdgcn_s_setprio(0);
    if (ktA + 2 < 8) loadV(ktA + 2, vb0);
    storeW(ktA);
    __builtin_amdgcn_s_setprio(1);
#pragma unroll
    for (int kk = 0; kk < 2; ++kk) {
      const int chunk = (ktB * 8 + kk * 4 + q4) ^ (qr & 7);
      bf16x8 pa = *reinterpret_cast<const bf16x8*>(Pr + chunk * 16);
#pragma unroll
      for (int ct = 0; ct < 4; ++ct)
        acc2[ct] = MFMA(pa, vb1[kk * 4 + ct], acc2[ct], 0, 0, 0);
    }
    __builtin_amdgcn_s_setprio(0);
    if (ktB + 2 < 8) loadV(ktB + 2, vb1);
    storeW(ktB);
  }

  // AO epilogue via dedicated LDS transpose tile
#pragma unroll
  for (int ct = 0; ct < 4; ++ct)
#pragma unroll
    for (int j3 = 0; j3 < 4; ++j3)
      ao_t[(wid * 16 + q4 * 4 + j3) * 72 + ct * 16 + l15] = f2b(acc2[ct][j3]);
  __syncthreads();
  {
    const int row = tid >> 3, ch = tid & 7;
#pragma unroll
    for (int i = 0; i < 2; ++i) {
      const int r = row + i * 32;
      int4 v = *reinterpret_cast<const int4*>(ao_t + r * 72 + ch * 8);
      *reinterpret_cast<int4*>(AO + ((size_t)b * Nn + q0 + r) * Ee + h * Dd + ch * 8) = v;
    }
  }
}

// ---------- K4: output projection GEMM (global_load_lds, all-bf16) -> f32 out (nt) ----------
__global__ __launch_bounds__(256, 4)
void k_outproj(const u16* __restrict__ AOp, const u16* __restrict__ Wo,
               const float* __restrict__ bo, float* __restrict__ out) {
  const int bm = blockIdx.x, bn = blockIdx.y;
  const int tid = threadIdx.x, lane = tid & 63, wid = tid >> 6;
  const int wr = wid >> 1, wc = wid & 1;

  __shared__ char smem[32768];   // A: 2x8KB at 0; B: 2x8KB at 16384

  auto stage = [&](const u16* src, int lds_base, int buf, int it) {
    const int r0 = tid >> 2, s = tid & 3;
    char* lbase = smem + lds_base + buf * 8192 + tid * 16;
#pragma unroll
    for (int R = 0; R < 2; ++R) {
      const int row = R * 64 + r0;
      const int ch = s ^ ((row >> 1) & 3);
      gload16(src + (size_t)row * Ee + it * 32 + ch * 8, lbase + R * 4096);
    }
  };

  f32x4 acc[4][4] = {};

  auto compute = [&](int buf) {
    const char* Ab = smem + buf * 8192;
    const char* Bbp = smem + 16384 + buf * 8192;
    const int q = lane >> 4;
    bf16x8 a[4], b[4];
#pragma unroll
    for (int mt = 0; mt < 4; ++mt) {
      const int row = wr * 64 + mt * 16 + (lane & 15);
      const int s = q ^ ((row >> 1) & 3);
      a[mt] = *reinterpret_cast<const bf16x8*>(Ab + row * 64 + s * 16);
    }
#pragma unroll
    for (int nt = 0; nt < 4; ++nt) {
      const int row = wc * 64 + nt * 16 + (lane & 15);
      const int s = q ^ ((row >> 1) & 3);
      b[nt] = *reinterpret_cast<const bf16x8*>(Bbp + row * 64 + s * 16);
    }
#pragma unroll
    for (int mt = 0; mt < 4; ++mt)
#pragma unroll
      for (int nt = 0; nt < 4; ++nt)
        acc[mt][nt] = MFMA(a[mt], b[nt], acc[mt][nt], 0, 0, 0);
  };

  const u16* Asrc = AOp + (size_t)(bm * 128) * Ee;
  const u16* Bsrc = Wo + (size_t)(bn * 128) * Ee;
  stage(Asrc, 0, 0, 0); stage(Bsrc, 16384, 0, 0);
  __syncthreads();
  int buf = 0;
  for (int it = 0; it < 24; ++it) {
    if (it + 1 < 24) { stage(Asrc, 0, buf ^ 1, it + 1); stage(Bsrc, 16384, buf ^ 1, it + 1); }
    compute(buf);
    __syncthreads();
    buf ^= 1;
  }

#pragma unroll
  for (int mt = 0; mt < 4; ++mt) {
#pragma unroll
    for (int nt = 0; nt < 4; ++nt) {
      const int ecol = bn * 128 + wc * 64 + nt * 16 + (lane & 15);
      const int r0 = bm * 128 + wr * 64 + mt * 16 + ((lane >> 4) << 2);
      const float bs = bo[ecol];
      f32x4 v = acc[mt][nt];
#pragma unroll
      for (int j = 0; j < 4; ++j)
        __builtin_nontemporal_store(v[j] + bs, &out[(size_t)(r0 + j) * Ee + ecol]);
    }
  }
}

// ---------- launch ----------
extern "C" void kernel_launch(void* const* d_in, const int* in_sizes, int n_in,
                              void* d_out, int out_size, void* d_ws, size_t ws_size,
                              hipStream_t stream) {
  const float* query  = (const float*)d_in[0];
  const float* key_in = (const float*)d_in[1];
  const float* value  = (const float*)d_in[2];
  const float* sb     = (const float*)d_in[3];
  const float* eb     = (const float*)d_in[4];
  const float* Wq     = (const float*)d_in[5];
  const float* bq     = (const float*)d_in[6];
  const float* Wk     = (const float*)d_in[7];
  const float* bk     = (const float*)d_in[8];
  const float* Wv     = (const float*)d_in[9];
  const float* bv     = (const float*)d_in[10];
  const float* Wo     = (const float*)d_in[11];
  const float* bo     = (const float*)d_in[12];

  float* out0 = (float*)d_out;                        // attn_output [16,512,768]
  float* wout = out0 + (size_t)Bb * Nn * Ee;          // attn_weights [16,12,512,512]

  // workspace layout (bytes)
  char* ws = (char*)d_ws;
  const size_t off_wb = 0;                 // 4 * 768*768 bf16 = 4,718,592
  const size_t off_Q  = 4718592;           // 12,582,912 each
  const size_t off_K  = 17301504;
  const size_t off_VT = 29884416;
  const size_t off_AO = 42467328;
  const size_t off_cb = 55050240;          // 16*512*512 bf16 = 8,388,608 -> end 63,438,848
  if (ws_size < 63438848) return;

  u16* wb  = (u16*)(ws + off_wb);
  u16* Qs  = (u16*)(ws + off_Q);
  u16* Kst = (u16*)(ws + off_K);
  u16* VTs = (u16*)(ws + off_VT);
  u16* AO  = (u16*)(ws + off_AO);
  u16* cbf = (u16*)(ws + off_cb);

  k_cvt<<<4352, 256, 0, stream>>>(Wq, Wk, Wv, Wo, wb, sb, eb, cbf);
  k_qkv<<<dim3(64, 6, 3), 256, 0, stream>>>(query, key_in, value, wb, bq, bk, bv, Qs, Kst, VTs);
  k_attn<<<dim3(8, Hh, Bb), 256, 0, stream>>>(Qs, Kst, cbf, VTs, wout, AO);
  k_outproj<<<dim3(64, 6), 256, 0, stream>>>(AO, wb + 3 * Ee * Ee, bo, out0);
}